// Round 3
// baseline (1339.509 us; speedup 1.0000x reference)
//
#include <hip/hip_runtime.h>
#include <hip/hip_bf16.h>

#define LL 24
#define NN 16384
#define HH 128
#define KP 288           // padded K: 16 op + 56 attr + 32 fd + 32 od + 24 zero + 128 gh
#define LN (LL*NN)

typedef __bf16 bf16;
typedef __attribute__((ext_vector_type(8))) __bf16 bf16x8;
typedef __attribute__((ext_vector_type(4))) __bf16 bf16x4;
typedef __attribute__((ext_vector_type(4))) float f32x4;

__device__ __forceinline__ float sigm(float x){ return 1.f/(1.f+__expf(-x)); }
__device__ __forceinline__ float tanhfast(float x){
    float e = __expf(-2.f*fabsf(x));
    float t = (1.f-e)/(1.f+e);
    return x >= 0.f ? t : -t;
}

// ---------------------------------------------------------------------------
// W split prep: Wsp = [ WH | WL ], each [KQ][32 ch][8 k] bf16.
// hi = bf16(w), lo = bf16(w - hi);  k >= D zero-padded.
// ---------------------------------------------------------------------------
template<int D, int KQ>
__global__ void prep_wsplit(const float* __restrict__ W, bf16* __restrict__ Wsp)
{
    for (int idx = threadIdx.x; idx < KQ*256; idx += blockDim.x) {
        const int j   = idx & 7;
        const int col = (idx >> 3) & 31;
        const int kq  = idx >> 8;
        const int k   = kq*8 + j;
        float v = (k < D) ? W[col*D + k] : 0.f;
        bf16 h = (bf16)v;
        Wsp[idx]          = h;
        Wsp[KQ*256 + idx] = (bf16)(v - (float)h);
    }
}

// ---------------------------------------------------------------------------
// act = leaky(X @ W.T + b) via split-bf16 MFMA, NO LDS / NO BARRIERS.
// B-fragment (lane&15=row, lane>>4=k-octet) = 8 contiguous floats of one X
// row -> direct global loads. Waves grid-stride independent 16-row tiles;
// compiler free to software-pipeline across tiles (no syncs).
// ---------------------------------------------------------------------------
template<int D, int KSTEPS>
__global__ __launch_bounds__(256) void act_direct(
    const float* __restrict__ X, const bf16* __restrict__ Wsp,
    const float* __restrict__ bias, bf16* __restrict__ act,
    float* __restrict__ sums)
{
    constexpr int KQ = KSTEPS*4;
    __shared__ float red[64];
    const int tid  = threadIdx.x;
    const int lane = tid & 63, w = tid >> 6;
    const int l15  = lane & 15, l4 = lane >> 4;

    if (tid < 64) red[tid] = 0.f;

    // W fragments in registers for the whole kernel
    bf16x8 wh[KSTEPS][2], wl[KSTEPS][2];
    #pragma unroll
    for (int ks=0; ks<KSTEPS; ++ks)
        #pragma unroll
        for (int cht=0; cht<2; ++cht) {
            const int idx = ((ks*4 + l4)*32 + cht*16 + l15)*8;
            wh[ks][cht] = *(const bf16x8*)&Wsp[idx];
            wl[ks][cht] = *(const bf16x8*)&Wsp[KQ*256 + idx];
        }
    float4 bb[2];
    #pragma unroll
    for (int cht=0; cht<2; ++cht) bb[cht] = *(const float4*)&bias[cht*16 + l4*4];

    float sst[2][4], ssq[2][4];
    #pragma unroll
    for (int c=0;c<2;++c)
        #pragma unroll
        for (int r=0;r<4;++r){ sst[c][r]=0.f; ssq[c][r]=0.f; }

    const int gw = blockIdx.x*4 + w, nw = gridDim.x*4;
    for (int tile = gw; tile < LN/16; tile += nw) {
        const long row = (long)tile*16 + l15;
        const float* xp = X + row*D;

        f32x4 acc[2];
        #pragma unroll
        for (int cht=0; cht<2; ++cht)
            acc[cht] = (f32x4){bb[cht].x, bb[cht].y, bb[cht].z, bb[cht].w};

        #pragma unroll
        for (int ks=0; ks<KSTEPS; ++ks) {
            const int k0 = ks*32 + l4*8;
            float xv[8];
            if constexpr (D % 32 == 0) {
                float4 a = *(const float4*)(xp + k0);
                float4 b = *(const float4*)(xp + k0 + 4);
                xv[0]=a.x; xv[1]=a.y; xv[2]=a.z; xv[3]=a.w;
                xv[4]=b.x; xv[5]=b.y; xv[6]=b.z; xv[7]=b.w;
            } else {
                const int rem = D - k0;
                if (rem >= 8) {                 // rows are only 8B-aligned: float2s
                    float2 p0 = *(const float2*)(xp + k0);
                    float2 p1 = *(const float2*)(xp + k0 + 2);
                    float2 p2 = *(const float2*)(xp + k0 + 4);
                    float2 p3 = *(const float2*)(xp + k0 + 6);
                    xv[0]=p0.x; xv[1]=p0.y; xv[2]=p1.x; xv[3]=p1.y;
                    xv[4]=p2.x; xv[5]=p2.y; xv[6]=p3.x; xv[7]=p3.y;
                } else {
                    #pragma unroll
                    for (int j=0;j<8;++j) xv[j] = (j < rem) ? xp[k0+j] : 0.f;
                }
            }
            bf16x8 xh, xl;
            #pragma unroll
            for (int j=0;j<8;++j){
                float x = xv[j];
                bf16 hh = (bf16)x;
                xh[j] = hh;
                xl[j] = (bf16)(x - (float)hh);
            }
            #pragma unroll
            for (int cht=0; cht<2; ++cht) {
                acc[cht] = __builtin_amdgcn_mfma_f32_16x16x32_bf16(wh[ks][cht], xh, acc[cht], 0,0,0);
                acc[cht] = __builtin_amdgcn_mfma_f32_16x16x32_bf16(wl[ks][cht], xh, acc[cht], 0,0,0);
                acc[cht] = __builtin_amdgcn_mfma_f32_16x16x32_bf16(wh[ks][cht], xl, acc[cht], 0,0,0);
            }
        }

        #pragma unroll
        for (int cht=0; cht<2; ++cht) {
            bf16x4 pk;
            #pragma unroll
            for (int reg=0; reg<4; ++reg) {
                float u = acc[cht][reg];
                u = u > 0.f ? u : 0.01f*u;
                pk[reg] = (bf16)u;
                sst[cht][reg] += u;
                ssq[cht][reg] += u*u;
            }
            *(bf16x4*)&act[row*32 + cht*16 + l4*4] = pk;
        }
    }

    __syncthreads();
    #pragma unroll
    for (int cht=0; cht<2; ++cht)
        #pragma unroll
        for (int reg=0; reg<4; ++reg) {
            const int ch = cht*16 + l4*4 + reg;
            atomicAdd(&red[ch],    sst[cht][reg]);
            atomicAdd(&red[32+ch], ssq[cht][reg]);
        }
    __syncthreads();
    if (tid < 64) atomicAdd(&sums[tid], red[tid]);
}

// ---------------------------------------------------------------------------
// BN scale/shift + collapse W2@W1 head.
// ---------------------------------------------------------------------------
__global__ void prep_stats(const float* __restrict__ stats,
    const float* __restrict__ g1, const float* __restrict__ beta1,
    const float* __restrict__ g2, const float* __restrict__ beta2,
    const float* __restrict__ W1, const float* __restrict__ b1,
    const float* __restrict__ W2, const float* __restrict__ b2,
    float* __restrict__ ss, float* __restrict__ wvb)
{
    const int t = threadIdx.x;
    const float inv = 1.f/(float)LN;
    if (t < 32) {
        float mean = stats[t]*inv;
        float var  = stats[32+t]*inv - mean*mean;
        float sc = g1[t]/sqrtf(var + 1e-5f);
        ss[t] = sc; ss[32+t] = beta1[t] - mean*sc;
    } else if (t < 64) {
        int c = t - 32;
        float mean = stats[64+c]*inv;
        float var  = stats[96+c]*inv - mean*mean;
        float sc = g2[c]/sqrtf(var + 1e-5f);
        ss[64+c] = sc; ss[96+c] = beta2[c] - mean*sc;
    }
    float s = 0.f;
    for (int a=0;a<20;++a) s += W2[a]*W1[a*HH + t];
    wvb[t] = s;
    if (t == 0) {
        float sb = 0.f;
        for (int a=0;a<20;++a) sb += W2[a]*b1[a];
        wvb[128] = sb + b2[0];
    }
}

// ---------------------------------------------------------------------------
// Wtb[n'][k] bf16 with BN FOLDED IN (fd/od cols pre-scaled by BN scale; BN
// shift folded into b4p in f32).  Gate-interleaved column permutation:
// n' = group*64 + gate*16 + c16  ->  orig j = gate*128 + group*16 + c16
// k: [0,72) raw Wih; [72,104) Wih*s1; [104,136) Wih*s2; [136,160) zero;
// [160,288) Whh.   b4p[n'] = bih+bhh + sum(t1*Wih_fd) + sum(t2*Wih_od).
// Runs AFTER prep_stats (needs ss).
// ---------------------------------------------------------------------------
__global__ void prep_wtb(const float* __restrict__ Wih, const float* __restrict__ Whh,
                         const float* __restrict__ bih, const float* __restrict__ bhh,
                         const float* __restrict__ ss,
                         bf16* __restrict__ Wtb, float* __restrict__ b4p)
{
    const int np = blockIdx.x;
    const int k  = threadIdx.x;
    const int gate = (np>>4)&3;
    const int j = gate*128 + (np>>6)*16 + (np&15);
    if (k < KP) {
        float v = 0.f;
        if (k < 72)        v = Wih[(long)j*136 + k];
        else if (k < 104)  v = Wih[(long)j*136 + k] * ss[k-72];
        else if (k < 136)  v = Wih[(long)j*136 + k] * ss[64 + (k-104)];
        else if (k >= 160) v = Whh[(long)j*128 + (k-160)];
        Wtb[(long)np*KP + k] = (bf16)v;
    }
    if (k == 0) {
        float b = bih[j] + bhh[j];
        for (int c=0;c<32;++c) {
            b += Wih[(long)j*136 + 72 + c]  * ss[32+c];
            b += Wih[(long)j*136 + 104 + c] * ss[96+c];
        }
        b4p[np] = b;
    }
}

// ---------------------------------------------------------------------------
// FUSED build_a + MFMA GEMM + LSTM cell.  NO LDS, NO BARRIERS.
// 128x128 tile, 4 waves 2x2, wave tile 64x64 = 4x4 of 16x16x32 MFMA.
// A-fragments (lane&15=row-offset, lane>>4=k-octet) built in registers
// directly from op/attr (f32->bf16), actf/acto (raw bf16; BN folded into
// Wtb/b4p), and gh = 0.5*(h[p0]+h[p1]) gathered per-lane (maps preloaded,
// shfl-broadcast).  B-fragments read straight from Wtb (L2-hot).
// first-step: gh == 0 -> k-steps 5..8 skipped entirely.
// ---------------------------------------------------------------------------
__global__ __launch_bounds__(256) void lstm_fused(
    const float* __restrict__ op, const float* __restrict__ attr,
    const bf16* __restrict__ actf, const bf16* __restrict__ acto,
    const bf16* __restrict__ Wtb, const float* __restrict__ b4p,
    const int* __restrict__ map, const bf16* __restrict__ h_prev,
    const float* __restrict__ c_prev, float* __restrict__ c_next,
    bf16* __restrict__ h_next, int l, int first)
{
    const int tid  = threadIdx.x;
    const int lane = tid & 63, w = tid >> 6;
    const int wr   = w >> 1,  wc = w & 1;
    const int l15  = lane & 15, l4 = lane >> 4;
    const int bm   = blockIdx.x, bn = blockIdx.y;
    const int m0   = bm*128, n0p = bn*128;
    const long lbase = (long)l * NN;

    f32x4 acc[4][4];
    #pragma unroll
    for (int ni=0; ni<4; ++ni){
        float b = b4p[n0p + wc*64 + ni*16 + l15];
        #pragma unroll
        for (int mi=0; mi<4; ++mi) acc[mi][ni] = (f32x4){b,b,b,b};
    }

    // wave's 64 rows: lane owns map of row (m0 + wr*64 + lane)
    int2 mp_l; mp_l.x = 0; mp_l.y = 0;
    if (!first) mp_l = *(const int2*)&map[(lbase + m0 + wr*64 + lane)*2];

    const long e0 = lbase + m0 + wr*64 + l15;          // + mi*16
    const bf16* Bb[4];
    #pragma unroll
    for (int ni=0; ni<4; ++ni)
        Bb[ni] = Wtb + (size_t)(n0p + wc*64 + ni*16 + l15)*KP + l4*8;

    auto f32frag = [](const float* p) -> bf16x8 {
        float4 a = *(const float4*)p, b = *(const float4*)(p+4);
        bf16x8 r;
        r[0]=(bf16)a.x; r[1]=(bf16)a.y; r[2]=(bf16)a.z; r[3]=(bf16)a.w;
        r[4]=(bf16)b.x; r[5]=(bf16)b.y; r[6]=(bf16)b.z; r[7]=(bf16)b.w;
        return r;
    };

    bf16x8 af[4], bfr[4];
    auto loadB = [&](int kk){
        #pragma unroll
        for (int ni=0; ni<4; ++ni) bfr[ni] = *(const bf16x8*)(Bb[ni] + kk*32);
    };
    auto mfma16 = [&](){
        #pragma unroll
        for (int mi=0; mi<4; ++mi)
            #pragma unroll
            for (int ni=0; ni<4; ++ni)
                acc[mi][ni] = __builtin_amdgcn_mfma_f32_16x16x32_bf16(
                    af[mi], bfr[ni], acc[mi][ni], 0, 0, 0);
    };

    // kk=0: op[0,16) for l4<2, attr[0,16) for l4>=2
    loadB(0);
    #pragma unroll
    for (int mi=0; mi<4; ++mi){
        const long e = e0 + mi*16;
        af[mi] = (l4 < 2) ? f32frag(op + e*16 + l4*8)
                          : f32frag(attr + e*56 + (l4-2)*8);
    }
    mfma16();
    // kk=1: attr[16,48)
    loadB(1);
    #pragma unroll
    for (int mi=0; mi<4; ++mi){
        const long e = e0 + mi*16;
        af[mi] = f32frag(attr + e*56 + 16 + l4*8);
    }
    mfma16();
    // kk=2: l4==0: attr[48,56); else fd[(l4-1)*8 ..)
    loadB(2);
    #pragma unroll
    for (int mi=0; mi<4; ++mi){
        const long e = e0 + mi*16;
        af[mi] = (l4 == 0) ? f32frag(attr + e*56 + 48)
                           : *(const bf16x8*)(actf + e*32 + (l4-1)*8);
    }
    mfma16();
    // kk=3: l4==0: fd[24,32); else od[(l4-1)*8 ..)
    loadB(3);
    #pragma unroll
    for (int mi=0; mi<4; ++mi){
        const long e = e0 + mi*16;
        af[mi] = (l4 == 0) ? *(const bf16x8*)(actf + e*32 + 24)
                           : *(const bf16x8*)(acto + e*32 + (l4-1)*8);
    }
    mfma16();
    // kk=4: l4==0: od[24,32); else zero-pad
    loadB(4);
    #pragma unroll
    for (int mi=0; mi<4; ++mi){
        const long e = e0 + mi*16;
        if (l4 == 0) af[mi] = *(const bf16x8*)(acto + e*32 + 24);
        else { bf16x8 z; 
               #pragma unroll
               for (int j=0;j<8;++j) z[j]=(bf16)0.f; af[mi]=z; }
    }
    mfma16();
    // kk=5..8: gh = 0.5*(h[p0]+h[p1])
    if (!first) {
        #pragma unroll
        for (int kk=5; kk<9; ++kk){
            loadB(kk);
            const int koff = (kk-5)*32 + l4*8;
            #pragma unroll
            for (int mi=0; mi<4; ++mi){
                const int src = mi*16 + l15;
                const int px = __shfl(mp_l.x, src);
                const int py = __shfl(mp_l.y, src);
                float g[8] = {0.f,0.f,0.f,0.f,0.f,0.f,0.f,0.f};
                if (px) {
                    bf16x8 v = *(const bf16x8*)&h_prev[(long)(px-1)*HH + koff];
                    #pragma unroll
                    for (int j=0;j<8;++j) g[j] += (float)v[j];
                }
                if (py) {
                    bf16x8 v = *(const bf16x8*)&h_prev[(long)(py-1)*HH + koff];
                    #pragma unroll
                    for (int j=0;j<8;++j) g[j] += (float)v[j];
                }
                bf16x8 r;
                #pragma unroll
                for (int j=0;j<8;++j) r[j] = (bf16)(0.5f*g[j]);
                af[mi] = r;
            }
            mfma16();
        }
    }

    // fused LSTM cell epilogue: gates i,f,g,o are acc[mi][0..3], same lane
    const int cell = bn*32 + wc*16 + l15;
    #pragma unroll
    for (int mi=0; mi<4; ++mi){
        #pragma unroll
        for (int reg=0; reg<4; ++reg){
            const int rloc = mi*16 + l4*4 + reg;       // row within wave
            const long n = m0 + wr*64 + rloc;
            float gc = 0.f;
            if (!first){
                const int px = __shfl(mp_l.x, rloc);
                const int py = __shfl(mp_l.y, rloc);
                if (px) gc += c_prev[(long)(px-1)*HH + cell];
                if (py) gc += c_prev[(long)(py-1)*HH + cell];
                gc *= 0.5f;
            }
            float cn = sigm(acc[mi][1][reg])*gc
                     + sigm(acc[mi][0][reg])*tanhfast(acc[mi][2][reg]);
            float hn = sigm(acc[mi][3][reg])*tanhfast(cn);
            c_next[n*HH + cell] = cn;
            h_next[n*HH + cell] = (bf16)hn;
        }
    }
}

// ---------------------------------------------------------------------------
// out[n] = sigmoid(h[n] . wv + wb); one wave per row.
// ---------------------------------------------------------------------------
__global__ __launch_bounds__(256) void final_k(
    const bf16* __restrict__ h, const float* __restrict__ wvb,
    float* __restrict__ out, int rows)
{
    int gt = blockIdx.x*256 + threadIdx.x;
    int row = gt >> 6;
    int lane = gt & 63;
    if (row >= rows) return;
    float v = fmaf((float)h[(long)row*HH + lane], wvb[lane],
                   (float)h[(long)row*HH + 64 + lane] * wvb[64+lane]);
    #pragma unroll
    for (int off=32; off>0; off>>=1) v += __shfl_down(v, off);
    if (lane == 0) out[row] = sigm(v + wvb[128]);
}

extern "C" void kernel_launch(void* const* d_in, const int* in_sizes, int n_in,
                              void* d_out, int out_size, void* d_ws, size_t ws_size,
                              hipStream_t stream)
{
    const float* op      = (const float*)d_in[0];
    const float* attr    = (const float*)d_in[1];
    const float* filt    = (const float*)d_in[2];
    const float* outp    = (const float*)d_in[3];
    const int*   mapping = (const int*)d_in[4];
    const float* Wf  = (const float*)d_in[6];
    const float* bf_ = (const float*)d_in[7];
    const float* Wo  = (const float*)d_in[8];
    const float* bo  = (const float*)d_in[9];
    const float* g1  = (const float*)d_in[10];
    const float* be1 = (const float*)d_in[11];
    const float* g2  = (const float*)d_in[12];
    const float* be2 = (const float*)d_in[13];
    const float* Wih = (const float*)d_in[14];
    const float* Whh = (const float*)d_in[15];
    const float* bih = (const float*)d_in[16];
    const float* bhh = (const float*)d_in[17];
    const float* W1  = (const float*)d_in[18];
    const float* b1  = (const float*)d_in[19];
    const float* W2  = (const float*)d_in[20];
    const float* b2  = (const float*)d_in[21];

    char* p = (char*)d_ws;
    auto alloc = [&](size_t bytes){ char* r = p; p += (bytes + 255) & ~255ull; return r; };
    bf16* actf = (bf16*)alloc((size_t)LN*32*2);
    bf16* acto = (bf16*)alloc((size_t)LN*32*2);
    bf16* h0   = (bf16*)alloc((size_t)NN*HH*2);
    bf16* h1   = (bf16*)alloc((size_t)NN*HH*2);
    float* c0  = (float*)alloc((size_t)NN*HH*4);
    float* c1  = (float*)alloc((size_t)NN*HH*4);
    bf16* Wtb  = (bf16*)alloc((size_t)512*KP*2);
    float* b4p = (float*)alloc(512*4);
    float* stats=(float*)alloc(128*4);
    float* ssb = (float*)alloc(128*4);
    float* wvb = (float*)alloc(132*4);
    bf16* wspf = (bf16*)alloc((size_t)12*256*2*2);   // [WH|WL] for Wf, KQ=12
    bf16* wspo = (bf16*)alloc((size_t)4*256*2*2);    // [WH|WL] for Wo, KQ=4

    hipMemsetAsync(stats, 0, 128*sizeof(float), stream);
    prep_wsplit<74,12><<<1, 256, 0, stream>>>(Wf, wspf);
    prep_wsplit<32, 4><<<1, 256, 0, stream>>>(Wo, wspo);
    act_direct<74,3><<<1024, 256, 0, stream>>>(filt, wspf, bf_, actf, stats);
    act_direct<32,1><<<1024, 256, 0, stream>>>(outp, wspo, bo, acto, stats+64);
    prep_stats<<<1, 128, 0, stream>>>(stats, g1, be1, g2, be2, W1, b1, W2, b2, ssb, wvb);
    prep_wtb<<<512, 320, 0, stream>>>(Wih, Whh, bih, bhh, ssb, Wtb, b4p);

    bf16*  hb[2] = {h0, h1};
    float* cb[2] = {c0, c1};
    for (int t = 0; t < LL; ++t) {
        const int l = (LL-1) - t;
        const int first = (t == 0);
        lstm_fused<<<dim3(128,4), 256, 0, stream>>>(op, attr, actf, acto,
            Wtb, b4p, mapping, hb[t&1],
            cb[t&1], cb[(t+1)&1], hb[(t+1)&1], l, first);
    }
    final_k<<<(out_size*64 + 255)/256, 256, 0, stream>>>(hb[0], wvb, (float*)d_out, out_size);
}